// Round 1
// baseline (92.163 us; speedup 1.0000x reference)
//
#include <hip/hip_runtime.h>

#define T_DIM 1024

// One block per (b,t). 256 threads.
// Phase 1 (conv): thread = output channel o in [0,256). 24 weights in regs,
//   x window in LDS (broadcast reads), writes U[32][257] to LDS (pad +1).
// Phase 2 (attention): thread = (n = tid>>4, j = tid&15); 16-lane-group
//   shuffle reductions for softmax and the final norm.
__global__ __launch_bounds__(256, 4) void caps_kernel(
    const float* __restrict__ x,     // (B,T,32,8)
    const float* __restrict__ K,     // (3,8,256)
    const float* __restrict__ bias,  // (256)
    const float* __restrict__ Bw,    // (T,16,1,32)
    float* __restrict__ out)         // (B,T,16,16)
{
    const int bt  = blockIdx.x;        // b*T + t
    const int t   = bt & (T_DIM - 1);
    const int tid = threadIdx.x;       // = o in conv phase

    __shared__ float xs[3][256];       // x[t-1..t+1] slice
    __shared__ float Ul[32 * 257];     // U[p][o], row stride 257 (bank pad)
    __shared__ float Vs[16][17];       // per-head column sums
    __shared__ float cs[16][33];       // per-head softmax+Bw coefficients

    // ---- load x window (coalesced; zero-pad t boundaries) ----
    const float* xb = x + (size_t)bt * 256;
    #pragma unroll
    for (int kt = 0; kt < 3; ++kt) {
        const int tt = t + kt - 1;
        xs[kt][tid] = (tt >= 0 && tt < T_DIM) ? xb[(kt - 1) * 256 + tid] : 0.f;
    }

    // ---- conv weights for this channel into registers (coalesced) ----
    float kw[3][8];
    #pragma unroll
    for (int kt = 0; kt < 3; ++kt)
        #pragma unroll
        for (int d = 0; d < 8; ++d)
            kw[kt][d] = K[(kt * 8 + d) * 256 + tid];
    const float bo = bias[tid];

    __syncthreads();

    // ---- conv + relu: U[p][o] ----
    #pragma unroll 4
    for (int p = 0; p < 32; ++p) {
        float acc = bo;
        #pragma unroll
        for (int kt = 0; kt < 3; ++kt) {
            const float4 a0 = *reinterpret_cast<const float4*>(&xs[kt][p * 8]);
            const float4 a1 = *reinterpret_cast<const float4*>(&xs[kt][p * 8 + 4]);
            acc = fmaf(a0.x, kw[kt][0], acc);
            acc = fmaf(a0.y, kw[kt][1], acc);
            acc = fmaf(a0.z, kw[kt][2], acc);
            acc = fmaf(a0.w, kw[kt][3], acc);
            acc = fmaf(a1.x, kw[kt][4], acc);
            acc = fmaf(a1.y, kw[kt][5], acc);
            acc = fmaf(a1.z, kw[kt][6], acc);
            acc = fmaf(a1.w, kw[kt][7], acc);
        }
        Ul[p * 257 + tid] = fmaxf(acc, 0.f);
    }

    __syncthreads();

    const int n = tid >> 4;   // head
    const int j = tid & 15;   // lane within head

    // ---- V[n][d] = sum_p U[p][n*16+d]   (tid == n*16+j) ----
    float v = 0.f;
    #pragma unroll 8
    for (int p = 0; p < 32; ++p) v += Ul[p * 257 + tid];
    Vs[n][j] = v;
    __syncthreads();

    // ---- s[q] = (V . U[q,:]) / sqrt(8), q = j and j+16 ----
    float s0 = 0.f, s1 = 0.f;
    #pragma unroll
    for (int d = 0; d < 16; ++d) {
        const float vd = Vs[n][d];
        s0 = fmaf(Ul[j * 257 + n * 16 + d], vd, s0);
        s1 = fmaf(Ul[(j + 16) * 257 + n * 16 + d], vd, s1);
    }
    const float inv_sqrt8 = 0.35355339059327373f;
    s0 *= inv_sqrt8;
    s1 *= inv_sqrt8;

    // ---- softmax over the 32 q's (16-lane-group shuffle reduce) ----
    float m = fmaxf(s0, s1);
    #pragma unroll
    for (int mask = 1; mask <= 8; mask <<= 1) m = fmaxf(m, __shfl_xor(m, mask));
    const float e0 = __expf(s0 - m), e1 = __expf(s1 - m);
    float es = e0 + e1;
    #pragma unroll
    for (int mask = 1; mask <= 8; mask <<= 1) es += __shfl_xor(es, mask);
    const float inv = 1.f / es;

    const float* bwp = Bw + (size_t)t * 512 + n * 32;  // (T,16,1,32)
    cs[n][j]      = e0 * inv + bwp[j];
    cs[n][j + 16] = e1 * inv + bwp[j + 16];
    __syncthreads();

    // ---- out[d=j] = sum_q c[q] * U[q][n*16+j] ----
    float od = 0.f;
    #pragma unroll 8
    for (int q = 0; q < 32; ++q) od = fmaf(cs[n][q], Ul[q * 257 + tid], od);

    // ---- norm gate: sq/(sq+1) * out/(norm+eps) ----
    float ss = od * od;
    #pragma unroll
    for (int mask = 1; mask <= 8; mask <<= 1) ss += __shfl_xor(ss, mask);
    const float nrm = sqrtf(ss);
    const float res = ss / (ss + 1.f) * (od / (nrm + 1e-7f));

    out[(size_t)bt * 256 + tid] = res;
}

extern "C" void kernel_launch(void* const* d_in, const int* in_sizes, int n_in,
                              void* d_out, int out_size, void* d_ws, size_t ws_size,
                              hipStream_t stream) {
    const float* x    = (const float*)d_in[0];
    const float* K    = (const float*)d_in[1];
    const float* bias = (const float*)d_in[2];
    const float* Bw   = (const float*)d_in[3];
    float* out        = (float*)d_out;

    const int B  = in_sizes[0] / (T_DIM * 32 * 8);   // = 8
    const int nb = B * T_DIM;                        // 8192 blocks

    caps_kernel<<<nb, 256, 0, stream>>>(x, K, bias, Bw, out);
}

// Round 2
// 71.221 us; speedup vs baseline: 1.2940x; 1.2940x over previous
//
#include <hip/hip_runtime.h>

#define T_DIM 1024

typedef float f32x16 __attribute__((ext_vector_type(16)));

// One block per (b,t), 256 threads, thread = output channel o.
// Conv: x-window rows are block-uniform -> s_load into SGPRs; 24 weights in
//   VGPRs; u[32] (column o of U) accumulated in registers.
// Scores: need U columns across the head -> one transposed LDS copy Ut[o][q]
//   (stride 36 floats, per-head rotate-8 swizzle -> <=2-way banks, 16B aligned).
// Everything else (V, out) stays in registers; softmax via 16-lane shuffles.
__global__ __launch_bounds__(256, 4) void caps_kernel(
    const float* __restrict__ x,     // (B,T,32,8)
    const float* __restrict__ K,     // (3,8,256)
    const float* __restrict__ bias,  // (256)
    const float* __restrict__ Bw,    // (T,16,1,32)
    float* __restrict__ out)         // (B,T,16,16)
{
    const int bt  = blockIdx.x;
    const int t   = bt & (T_DIM - 1);
    const int tid = threadIdx.x;

    __shared__ float Ut[256 * 36];   // U^T: row o holds U[0..31][o], swizzled
    __shared__ float Vs[256];        // V[o] = sum_p U[p][o]
    __shared__ float cs[16 * 36];    // per-head softmax+Bw coefficients

    // ---- conv weights into registers (coalesced, L2-resident) ----
    float kw[3][8];
    #pragma unroll
    for (int kt = 0; kt < 3; ++kt)
        #pragma unroll
        for (int d = 0; d < 8; ++d)
            kw[kt][d] = K[(kt * 8 + d) * 256 + tid];
    const float bo = bias[tid];

    // t-boundary: clamp row offset to a safe row, zero that kernel row
    if (t == 0) {
        #pragma unroll
        for (int d = 0; d < 8; ++d) kw[0][d] = 0.f;
    }
    if (t == T_DIM - 1) {
        #pragma unroll
        for (int d = 0; d < 8; ++d) kw[2][d] = 0.f;
    }

    const float* xm1 = x + (size_t)bt * 256 - 256;          // row t-1
    const unsigned offA = (t == 0) ? 1024u : 0u;            // bytes
    const unsigned offB = 1024u;
    const unsigned offC = (t == T_DIM - 1) ? 1024u : 2048u;

    // ---- conv + relu, u[p] in registers; x rows via scalar loads ----
    float u[32];
    #pragma unroll
    for (int pp = 0; pp < 16; ++pp) {      // two p per step: 16 floats per kt row
        f32x16 r0, r1, r2;
        asm volatile(
            "s_load_dwordx16 %0, %3, %4\n\t"
            "s_load_dwordx16 %1, %3, %5\n\t"
            "s_load_dwordx16 %2, %3, %6\n\t"
            "s_waitcnt lgkmcnt(0)"
            : "=s"(r0), "=s"(r1), "=s"(r2)
            : "s"(xm1), "s"(offA + pp * 64u), "s"(offB + pp * 64u),
              "s"(offC + pp * 64u));
        float a0 = bo, a1 = bo;
        #pragma unroll
        for (int d = 0; d < 8; ++d) {
            a0 = fmaf(r0[d], kw[0][d], a0);  a1 = fmaf(r0[8 + d], kw[0][d], a1);
            a0 = fmaf(r1[d], kw[1][d], a0);  a1 = fmaf(r1[8 + d], kw[1][d], a1);
            a0 = fmaf(r2[d], kw[2][d], a0);  a1 = fmaf(r2[8 + d], kw[2][d], a1);
        }
        u[2 * pp]     = fmaxf(a0, 0.f);
        u[2 * pp + 1] = fmaxf(a1, 0.f);
    }

    // ---- V[o] in registers (pairwise) ----
    float v4[8];
    #pragma unroll
    for (int k = 0; k < 8; ++k)
        v4[k] = (u[4 * k] + u[4 * k + 1]) + (u[4 * k + 2] + u[4 * k + 3]);
    const float V = ((v4[0] + v4[1]) + (v4[2] + v4[3])) +
                    ((v4[4] + v4[5]) + (v4[6] + v4[7]));

    const int n = tid >> 4, j = tid & 15;
    const int rot = (n & 3) * 8;            // per-head slot rotation (bank split)

    // ---- store U^T (8x ds_write_b128, 16B aligned, <=2-way banks) ----
    #pragma unroll
    for (int k = 0; k < 8; ++k) {
        const int slot = (4 * k + rot) & 31;
        *reinterpret_cast<float4*>(&Ut[tid * 36 + slot]) =
            make_float4(u[4 * k], u[4 * k + 1], u[4 * k + 2], u[4 * k + 3]);
    }
    Vs[tid] = V;
    __syncthreads();

    // ---- scores s[q] = (V . U[q,:]) / sqrt(8) for q = j, j+16 ----
    const int sq0 = (j + rot) & 31;
    const int sq1 = (j + 16 + rot) & 31;
    float s0 = 0.f, s1 = 0.f;
    #pragma unroll
    for (int kk = 0; kk < 4; ++kk) {
        const float4 vq = *reinterpret_cast<const float4*>(&Vs[n * 16 + 4 * kk]);
        const float* up = &Ut[(n * 16 + 4 * kk) * 36];
        s0 = fmaf(up[0 * 36 + sq0], vq.x, s0);  s1 = fmaf(up[0 * 36 + sq1], vq.x, s1);
        s0 = fmaf(up[1 * 36 + sq0], vq.y, s0);  s1 = fmaf(up[1 * 36 + sq1], vq.y, s1);
        s0 = fmaf(up[2 * 36 + sq0], vq.z, s0);  s1 = fmaf(up[2 * 36 + sq1], vq.z, s1);
        s0 = fmaf(up[3 * 36 + sq0], vq.w, s0);  s1 = fmaf(up[3 * 36 + sq1], vq.w, s1);
    }
    const float inv_sqrt8 = 0.35355339059327373f;
    s0 *= inv_sqrt8;
    s1 *= inv_sqrt8;

    // ---- softmax over 32 q (16-lane-group shuffles) ----
    float m = fmaxf(s0, s1);
    #pragma unroll
    for (int mask = 1; mask <= 8; mask <<= 1) m = fmaxf(m, __shfl_xor(m, mask));
    const float e0 = __expf(s0 - m), e1 = __expf(s1 - m);
    float es = e0 + e1;
    #pragma unroll
    for (int mask = 1; mask <= 8; mask <<= 1) es += __shfl_xor(es, mask);
    const float inv = 1.f / es;

    const float* bwp = Bw + (size_t)t * 512 + n * 32;   // (T,16,1,32)
    cs[n * 36 + j]      = fmaf(e0, inv, bwp[j]);
    cs[n * 36 + j + 16] = fmaf(e1, inv, bwp[j + 16]);
    __syncthreads();

    // ---- out[o] = sum_q c[q] * u[q]  (registers + broadcast c) ----
    float od = 0.f;
    #pragma unroll
    for (int k = 0; k < 8; ++k) {
        const float4 cq = *reinterpret_cast<const float4*>(&cs[n * 36 + 4 * k]);
        od = fmaf(cq.x, u[4 * k],     od);
        od = fmaf(cq.y, u[4 * k + 1], od);
        od = fmaf(cq.z, u[4 * k + 2], od);
        od = fmaf(cq.w, u[4 * k + 3], od);
    }

    // ---- norm gate ----
    float ss = od * od;
    #pragma unroll
    for (int mask = 1; mask <= 8; mask <<= 1) ss += __shfl_xor(ss, mask);
    const float nrm = sqrtf(ss);
    out[(size_t)bt * 256 + tid] = ss / (ss + 1.f) * (od / (nrm + 1e-7f));
}

extern "C" void kernel_launch(void* const* d_in, const int* in_sizes, int n_in,
                              void* d_out, int out_size, void* d_ws, size_t ws_size,
                              hipStream_t stream) {
    const float* x    = (const float*)d_in[0];
    const float* K    = (const float*)d_in[1];
    const float* bias = (const float*)d_in[2];
    const float* Bw   = (const float*)d_in[3];
    float* out        = (float*)d_out;

    const int B  = in_sizes[0] / (T_DIM * 32 * 8);   // = 8
    const int nb = B * T_DIM;                        // 8192 blocks

    caps_kernel<<<nb, 256, 0, stream>>>(x, K, bias, Bw, out);
}

// Round 3
// 44.914 us; speedup vs baseline: 2.0520x; 1.5857x over previous
//
#include <hip/hip_runtime.h>

#define T_DIM 1024

typedef short short8 __attribute__((ext_vector_type(8)));
typedef float f32x4  __attribute__((ext_vector_type(4)));

__device__ __forceinline__ short f2bf(float f) {   // RNE float->bf16
    unsigned u = __float_as_uint(f);
    u += 0x7fffu + ((u >> 16) & 1u);
    return (short)(u >> 16);
}

// One block per (b,t), 256 threads = 4 waves.
// Conv as MFMA: U[32x256] = X[32x32] * Kmat[32x256] (bf16, K padded 24->32).
//   Wave w owns output cols [w*64, w*64+64): 2 M-tiles x 4 N-tiles.
// Ut[o][slot(p)] f32 in LDS, per-head rotated p-slots (bank-conflict-free).
// Phase 2 (thread=o): V/scores/softmax/out vectorized, intra-wave shuffles.
__global__ __launch_bounds__(256, 3) void caps_kernel(
    const float* __restrict__ x,     // (B,T,32,8)
    const float* __restrict__ K,     // (3,8,256) flat (kt*8+d)*256+o
    const float* __restrict__ bias,  // (256)
    const float* __restrict__ Bw,    // (T,16,1,32)
    float* __restrict__ out)         // (B,T,16,16)
{
    const int bt  = blockIdx.x;
    const int t   = bt & (T_DIM - 1);
    const int tid = threadIdx.x;
    const int l   = tid & 63;
    const int w   = tid >> 6;

    __shared__ short Xs[32 * 40];    // X[p][k] bf16, row stride 40 (80B, 16B-aligned)
    __shared__ float bias_s[256];
    __shared__ float Ut[256 * 36];   // Ut[o][slot(p)], rot(o)=((o>>4)&3)*8
    __shared__ float Vs[256];
    __shared__ float cs[16 * 36];

    // ---- stage bias + X (3 coalesced rows, zero-pad t edges) ----
    bias_s[tid] = bias[tid];
    {
        const float* xb = x + (size_t)bt * 256;
        const int p = tid >> 3, d = tid & 7;
        #pragma unroll
        for (int kt = 0; kt < 3; ++kt) {
            const int tt = t + kt - 1;
            const float v = (tt >= 0 && tt < T_DIM) ? xb[(kt - 1) * 256 + tid] : 0.f;
            Xs[p * 40 + kt * 8 + d] = f2bf(v);
        }
    }
    __syncthreads();

    // ---- fragments ----
    const int kb  = l >> 4;          // k-block: lane holds k = kb*8..kb*8+7
    const int r16 = l & 15;

    short8 a0 = {}, a1 = {};
    if (kb < 3) {                    // kb==3 is the K-padding -> zeros
        a0 = *reinterpret_cast<const short8*>(&Xs[r16 * 40 + kb * 8]);
        a1 = *reinterpret_cast<const short8*>(&Xs[(16 + r16) * 40 + kb * 8]);
    }

    short8 bf[4];
    f32x4  acc[2][4];
    #pragma unroll
    for (int i = 0; i < 4; ++i) {
        bf[i] = (short8){};
        acc[0][i] = (f32x4){0.f, 0.f, 0.f, 0.f};
        acc[1][i] = (f32x4){0.f, 0.f, 0.f, 0.f};
    }
    if (kb < 3) {
        #pragma unroll
        for (int i = 0; i < 4; ++i) {
            const int col = w * 64 + i * 16 + r16;
            const float* kp = K + kb * 8 * 256 + col;
            #pragma unroll
            for (int e = 0; e < 8; ++e)
                bf[i][e] = f2bf(kp[e * 256]);
        }
    }

    #pragma unroll
    for (int i = 0; i < 4; ++i) {
        acc[0][i] = __builtin_amdgcn_mfma_f32_16x16x32_bf16(a0, bf[i], acc[0][i], 0, 0, 0);
        acc[1][i] = __builtin_amdgcn_mfma_f32_16x16x32_bf16(a1, bf[i], acc[1][i], 0, 0, 0);
    }

    // ---- epilogue: bias+relu -> Ut (float4 writes, rotated slots) ----
    #pragma unroll
    for (int mi = 0; mi < 2; ++mi) {
        #pragma unroll
        for (int i = 0; i < 4; ++i) {
            const int col  = w * 64 + i * 16 + r16;
            const float bo = bias_s[col];
            const int rot  = ((col >> 4) & 3) * 8;
            const int slot = (mi * 16 + kb * 4 + rot) & 31;
            float4 vw;
            vw.x = fmaxf(acc[mi][i][0] + bo, 0.f);
            vw.y = fmaxf(acc[mi][i][1] + bo, 0.f);
            vw.z = fmaxf(acc[mi][i][2] + bo, 0.f);
            vw.w = fmaxf(acc[mi][i][3] + bo, 0.f);
            *reinterpret_cast<float4*>(&Ut[col * 36 + slot]) = vw;
        }
    }
    __syncthreads();

    // ---- phase 2: thread = o = tid ----
    const int n = tid >> 4, j = tid & 15;
    const int rot2 = (n & 3) * 8;

    float4 u4[8];
    float V = 0.f;
    #pragma unroll
    for (int k = 0; k < 8; ++k) {
        u4[k] = *reinterpret_cast<const float4*>(&Ut[tid * 36 + 4 * k]);
        V += (u4[k].x + u4[k].y) + (u4[k].z + u4[k].w);
    }
    Vs[tid] = V;
    __syncthreads();

    // scores s[q] = (V_head . U[q,:]) / sqrt(8), q = j and j+16 (slot space)
    const int slot0 = (j + rot2) & 31;
    const int slot1 = slot0 ^ 16;
    float s0 = 0.f, s1 = 0.f;
    #pragma unroll
    for (int kk = 0; kk < 4; ++kk) {
        const float4 vq = *reinterpret_cast<const float4*>(&Vs[n * 16 + 4 * kk]);
        const float* up = &Ut[(n * 16 + 4 * kk) * 36];
        s0 = fmaf(up[0 * 36 + slot0], vq.x, s0);  s1 = fmaf(up[0 * 36 + slot1], vq.x, s1);
        s0 = fmaf(up[1 * 36 + slot0], vq.y, s0);  s1 = fmaf(up[1 * 36 + slot1], vq.y, s1);
        s0 = fmaf(up[2 * 36 + slot0], vq.z, s0);  s1 = fmaf(up[2 * 36 + slot1], vq.z, s1);
        s0 = fmaf(up[3 * 36 + slot0], vq.w, s0);  s1 = fmaf(up[3 * 36 + slot1], vq.w, s1);
    }
    const float inv_sqrt8 = 0.35355339059327373f;
    s0 *= inv_sqrt8;
    s1 *= inv_sqrt8;

    // softmax over 32 q (16-lane-group shuffles)
    float m = fmaxf(s0, s1);
    #pragma unroll
    for (int mask = 1; mask <= 8; mask <<= 1) m = fmaxf(m, __shfl_xor(m, mask));
    const float e0 = __expf(s0 - m), e1 = __expf(s1 - m);
    float es = e0 + e1;
    #pragma unroll
    for (int mask = 1; mask <= 8; mask <<= 1) es += __shfl_xor(es, mask);
    const float inv = 1.f / es;

    const float* bwp = Bw + (size_t)t * 512 + n * 32;   // (T,16,1,32)
    cs[n * 36 + slot0] = fmaf(e0, inv, bwp[j]);
    cs[n * 36 + slot1] = fmaf(e1, inv, bwp[j + 16]);
    __syncthreads();

    // out[o] = sum_q c[q] * U[q][o]  (slot space on both)
    float od = 0.f;
    #pragma unroll
    for (int k = 0; k < 8; ++k) {
        const float4 cq = *reinterpret_cast<const float4*>(&cs[n * 36 + 4 * k]);
        od = fmaf(cq.x, u4[k].x, od);
        od = fmaf(cq.y, u4[k].y, od);
        od = fmaf(cq.z, u4[k].z, od);
        od = fmaf(cq.w, u4[k].w, od);
    }

    // norm gate
    float ss = od * od;
    #pragma unroll
    for (int mask = 1; mask <= 8; mask <<= 1) ss += __shfl_xor(ss, mask);
    const float nrm = sqrtf(ss);
    out[(size_t)bt * 256 + tid] = ss / (ss + 1.f) * (od / (nrm + 1e-7f));
}

extern "C" void kernel_launch(void* const* d_in, const int* in_sizes, int n_in,
                              void* d_out, int out_size, void* d_ws, size_t ws_size,
                              hipStream_t stream) {
    const float* x    = (const float*)d_in[0];
    const float* K    = (const float*)d_in[1];
    const float* bias = (const float*)d_in[2];
    const float* Bw   = (const float*)d_in[3];
    float* out        = (float*)d_out;

    const int B  = in_sizes[0] / (T_DIM * 32 * 8);   // = 8
    const int nb = B * T_DIM;                        // 8192 blocks

    caps_kernel<<<nb, 256, 0, stream>>>(x, K, bias, Bw, out);
}